// Round 11
// baseline (130.319 us; speedup 1.0000x reference)
//
#include <hip/hip_runtime.h>
#include <hip/hip_bf16.h>

// ContrastiveLoss: loss = mean_i [ logsumexp_j(logits[i,:]) - pos_sim[i,i] ]
// logits = [20*xn@tn^T | 20*xn@hn^T + I], rows normalized.
// Round 19: pipeline AND residency. R18 isolated the variables:
//   residency 2->4 blocks/CU = 1.7x (R13); counted-vmcnt pipeline = +16%
//   iso-residency (R18 at 3 blk: 52.2 vs pure-scaling 60.8); but R18's
//   48KB LDS cost a block. This round fits the pipeline in 32KB:
//   BK=64, 2 slots x 16KB, depth-1 prefetch -> 4 blocks/CU preserved.
// Schedule (race-free; vmcnt BEFORE barrier so the barrier publishes all
// waves' DMA): iter k: vmcnt(0) [stage(k), issued ONE EPOCH ago -> drain
// nearly free] -> s_barrier [tile k visible; tile k-1 reads fenced] ->
// STAGE(k+1) [overwrites tile k-1's slot, post-barrier safe] -> compute(k).
// Only delta vs R15: stage issued one epoch before its drain (T3 minimum
// 2-phase recipe) instead of immediately before.
//  - Staging+swizzle = R18 verbatim (measured 0 conflicts at BK=64):
//    st_c = (t&3)^((t>>3)&3); frag cph = (quad ^ ((colid>>1)&3))*16.
//  - Ledger: no-LDS banned (R16); 32x32x32 banned (R17: 4.2M conflicts);
//    device fences banned (R14); scaled-MFMA banned (R2/R4); b64 reads
//    banned (R5); setprio off (m190). 2D XCD partition proven (R14/R15).
//  - logit = acc * (20/127^2); diag cancellation keeps i8 loss error ~1e-3.

#define AS1 __attribute__((address_space(1)))
#define AS3 __attribute__((address_space(3)))

constexpr int N = 4096;
constexpr int D = 1024;            // elements per row == bytes per i8 row
constexpr float QSCALE = 127.0f;
constexpr float LSCALE = 20.0f / (127.0f * 127.0f);  // acc -> logit
constexpr float CBIAS = 21.0f;     // >= max possible logit (20*1 + 1)

typedef int i32x4 __attribute__((ext_vector_type(4)));

// 3072 blocks x 256. One row per wave, 4 coalesced passes: pass j, lane L
// loads float4 #(L+64j) (1KB/inst contiguous) and stores the 4 quantized
// bytes as u32 #(L+64j) (256B/inst contiguous).
// Blocks 0..15 zero rowsum; block 0 zeroes out[0] for finalize's atomics.
__global__ __launch_bounds__(256) void normalize_kernel(
    const float* __restrict__ in0, const float* __restrict__ in1,
    const float* __restrict__ in2, unsigned char* __restrict__ Abuf,
    unsigned char* __restrict__ Bbuf, float* __restrict__ rowsum,
    float* __restrict__ outp) {
    const int t = threadIdx.x, lane = t & 63, wave = t >> 6;
    if (blockIdx.x < 16) rowsum[blockIdx.x * 256 + t] = 0.f;
    if (blockIdx.x == 0 && t == 0) outp[0] = 0.f;
    const int row = blockIdx.x * 4 + wave;  // 0..12287
    const int mat = row >> 12, r = row & (N - 1);
    const float* src = (mat == 0) ? in0 : (mat == 1) ? in1 : in2;
    unsigned char* dst = (mat == 0) ? (Abuf + (size_t)r * D)
                       : (mat == 1) ? (Bbuf + (size_t)r * D)
                                    : (Bbuf + (size_t)(r + N) * D);
    const float4* s4 = (const float4*)(src + (size_t)r * D);
    float4 v[4];
    float p = 0.f;
#pragma unroll
    for (int j = 0; j < 4; ++j) {
        v[j] = s4[lane + 64 * j];  // coalesced: 64 consecutive float4/inst
        p += v[j].x * v[j].x + v[j].y * v[j].y + v[j].z * v[j].z + v[j].w * v[j].w;
    }
#pragma unroll
    for (int m = 1; m < 64; m <<= 1) p += __shfl_xor(p, m);
    const float s = QSCALE / fmaxf(sqrtf(p), 1e-8f);
    unsigned int* d32 = (unsigned int*)dst;
#pragma unroll
    for (int j = 0; j < 4; ++j) {
        int q0 = min(127, max(-127, __float2int_rn(v[j].x * s)));
        int q1 = min(127, max(-127, __float2int_rn(v[j].y * s)));
        int q2 = min(127, max(-127, __float2int_rn(v[j].z * s)));
        int q3 = min(127, max(-127, __float2int_rn(v[j].w * s)));
        d32[lane + 64 * j] = (q0 & 255) | ((q1 & 255) << 8) | ((q2 & 255) << 16)
                           | ((unsigned)(q3 & 255) << 24);
    }
}

// 128x128 tile, BK=64 i8-bytes, 16 K-tiles, 4 waves 2x2, wave 64x64 via
// 4x4 of 16x16x64 i8 MFMA per K-tile, b128 frag reads.
// A:[N,D] i8, B:[2N,D] i8, row-major (frag = 16 contig bytes,
// row = lane&15, k = (lane>>4)*16 + j).
// C/D: col = lane&15, row = (lane>>4)*4 + reg (m89-verified).
// 2-slot ping-pong (slot = A 8KB | B 8KB), depth-1 prefetch, vmcnt(0)
// drain of an epoch-old stage (cheap) + one raw barrier per K-tile.
// __launch_bounds__(256,4) + 32KB LDS -> 4 blocks/CU (R13's proven lever).
__global__ __launch_bounds__(256, 4) void gemm_lse_kernel(
    const unsigned char* __restrict__ A, const unsigned char* __restrict__ B,
    float* __restrict__ rowsum, float* __restrict__ posdiag) {
    __shared__ __align__(16) char smem[2 * 16384];  // 32 KiB -> 4 blocks/CU

    const int tid = threadIdx.x;
    const int lane = tid & 63;
    const int wave = tid >> 6;
    const int wr = wave >> 1, wc = wave & 1;
    const int quad = lane >> 4, colid = lane & 15;

    // 2D XCD partition (R14/R15-proven: FETCH 39->16.5MB): XCD x owns the
    // 16x16-tile region rows [16*(x>>2),+16) x cols [16*(x&3),+16).
    const int flat = blockIdx.y * 64 + blockIdx.x;
    const int xcd = flat & 7, tt = flat >> 3;  // tt = 0..255 within XCD
    const int rowBase = (((xcd >> 2) << 4) + (tt & 15)) * 128;
    const int colBase = (((xcd & 3) << 4) + (tt >> 4)) * 128;

    i32x4 acc[4][4];
#pragma unroll
    for (int i = 0; i < 4; ++i)
#pragma unroll
        for (int j = 0; j < 4; ++j) acc[i][j] = {0, 0, 0, 0};

    // Staging (R18-verified, 0 conflicts at BK=64): per tile, panel = 128
    // rows x 64B = 512 16B-chunks per matrix; thread t writes chunks t
    // (rows 0..63) and t+256 (rows 64..127) at linear LDS byte (t+256j)*16.
    // Phys chunk c: row c>>2, phys col c&3; logical col = (c&3)^((row>>1)&3)
    // = (t&3)^((t>>3)&3) (j-invariant).
    const int st_row = tid >> 2;                    // 0..63
    const int st_c = (tid & 3) ^ ((tid >> 3) & 3);  // 16B units in 64B row
    const unsigned char* pA0 = A + (size_t)(rowBase + st_row) * D + st_c * 16;
    const unsigned char* pA1 = A + (size_t)(rowBase + st_row + 64) * D + st_c * 16;
    const unsigned char* pB0 = B + (size_t)(colBase + st_row) * D + st_c * 16;
    const unsigned char* pB1 = B + (size_t)(colBase + st_row + 64) * D + st_c * 16;

    // Frag read (R18-verified): row R = (wr|wc)*64 + rt*16 + colid;
    // (R>>1)&3 == (colid>>1)&3. Logical chunk = quad; phys = quad ^
    // ((colid>>1)&3). rt stride 16*64 = 1024 (immediate).
    const int cph = (quad ^ ((colid >> 1) & 3)) * 16;
    const int abase = (wr * 64 + colid) * 64 + cph;         // slot A half
    const int bbase = 8192 + (wc * 64 + colid) * 64 + cph;  // slot B half

#define STAGE(KT, SL)                                                        \
    {                                                                        \
        char* dst_ = smem + (SL) * 16384;                                    \
        __builtin_amdgcn_global_load_lds((const AS1 void*)(pA0 + (KT) * 64), \
            (AS3 void*)(dst_ + tid * 16), 16, 0, 0);                         \
        __builtin_amdgcn_global_load_lds((const AS1 void*)(pA1 + (KT) * 64), \
            (AS3 void*)(dst_ + (tid + 256) * 16), 16, 0, 0);                 \
        __builtin_amdgcn_global_load_lds((const AS1 void*)(pB0 + (KT) * 64), \
            (AS3 void*)(dst_ + 8192 + tid * 16), 16, 0, 0);                  \
        __builtin_amdgcn_global_load_lds((const AS1 void*)(pB1 + (KT) * 64), \
            (AS3 void*)(dst_ + 8192 + (tid + 256) * 16), 16, 0, 0);          \
    }

#define COMPUTE(SL)                                                          \
    {                                                                        \
        const char* s_ = smem + (SL) * 16384;                                \
        i32x4 a[4], b[4];                                                    \
        _Pragma("unroll") for (int rt = 0; rt < 4; ++rt)                     \
            a[rt] = *(const i32x4*)(s_ + abase + rt * 1024);                 \
        _Pragma("unroll") for (int ct = 0; ct < 4; ++ct)                     \
            b[ct] = *(const i32x4*)(s_ + bbase + ct * 1024);                 \
        _Pragma("unroll") for (int rt = 0; rt < 4; ++rt)                     \
            _Pragma("unroll") for (int ct = 0; ct < 4; ++ct)                 \
                acc[rt][ct] = __builtin_amdgcn_mfma_i32_16x16x64_i8(         \
                    a[rt], b[ct], acc[rt][ct], 0, 0, 0);                     \
    }

    // Prologue: stage tile 0 into slot 0.
    STAGE(0, 0)

    // iter k: drain stage(k) (issued one epoch ago -> wait ~free), publish
    // via barrier (also fences tile k-1 reads), prefetch tile k+1 into the
    // other slot, compute tile k.
#pragma unroll
    for (int k = 0; k < 16; ++k) {
        asm volatile("s_waitcnt vmcnt(0)" ::: "memory");
        __builtin_amdgcn_s_barrier();
        if (k < 15) {
            if ((k & 1) == 0) STAGE(k + 1, 1) else STAGE(k + 1, 0)
        }
        if ((k & 1) == 0) COMPUTE(0) else COMPUTE(1)
    }
#undef STAGE
#undef COMPUTE

    // Epilogue: C map col = lane&15, row = quad*4 + reg (R15 verbatim).
#pragma unroll
    for (int rt = 0; rt < 4; ++rt) {
        float rsum[4] = {0.f, 0.f, 0.f, 0.f};
#pragma unroll
        for (int ct = 0; ct < 4; ++ct) {
#pragma unroll
            for (int reg = 0; reg < 4; ++reg) {
                const int grow = rowBase + wr * 64 + rt * 16 + quad * 4 + reg;
                const int gcol = colBase + wc * 64 + ct * 16 + colid;
                float logit = (float)acc[rt][ct][reg] * LSCALE;
                if (gcol == grow + N) logit += 1.0f;      // hard-negative weight
                if (gcol == grow) posdiag[grow] = logit;  // unique writer
                rsum[reg] += __expf(logit - CBIAS);
            }
        }
#pragma unroll
        for (int reg = 0; reg < 4; ++reg) {
            float v = rsum[reg];
            v += __shfl_xor(v, 1);
            v += __shfl_xor(v, 2);
            v += __shfl_xor(v, 4);
            v += __shfl_xor(v, 8);
            if (colid == 0) {
                const int grow = rowBase + wr * 64 + rt * 16 + quad * 4 + reg;
                atomicAdd(&rowsum[grow], v);
            }
        }
    }
}

// 16 blocks x 256 thr, one row per thread; wave-reduce then one atomic per
// wave into out (out zeroed by normalize earlier in the stream).
__global__ __launch_bounds__(256) void finalize_kernel(
    const float* __restrict__ rowsum, const float* __restrict__ posdiag,
    float* __restrict__ out) {
    const int i = blockIdx.x * 256 + threadIdx.x;
    float s = CBIAS + logf(rowsum[i]) - posdiag[i];
#pragma unroll
    for (int m = 32; m; m >>= 1) s += __shfl_down(s, m);
    if ((threadIdx.x & 63) == 0) atomicAdd(out, s * (1.0f / (float)N));
}

extern "C" void kernel_launch(void* const* d_in, const int* in_sizes, int n_in,
                              void* d_out, int out_size, void* d_ws, size_t ws_size,
                              hipStream_t stream) {
    const float* in0 = (const float*)d_in[0];  // input   [N, D] fp32
    const float* in1 = (const float*)d_in[1];  // target  [N, D] fp32
    const float* in2 = (const float*)d_in[2];  // hardneg [N, D] fp32

    // Workspace: Abuf N*D i8 (4 MiB) | Bbuf 2N*D i8 (8 MiB) | rowsum | posdiag
    unsigned char* Abuf = (unsigned char*)d_ws;
    unsigned char* Bbuf = Abuf + (size_t)N * D;
    float* rowsum = (float*)(Bbuf + (size_t)2 * N * D);
    float* posdiag = rowsum + N;

    normalize_kernel<<<3 * N / 4, 256, 0, stream>>>(in0, in1, in2, Abuf, Bbuf,
                                                    rowsum, (float*)d_out);
    gemm_lse_kernel<<<dim3(2 * N / 128, N / 128), 256, 0, stream>>>(
        Abuf, Bbuf, rowsum, posdiag);
    finalize_kernel<<<16, 256, 0, stream>>>(rowsum, posdiag, (float*)d_out);
}

// Round 12
// 128.140 us; speedup vs baseline: 1.0170x; 1.0170x over previous
//
#include <hip/hip_runtime.h>
#include <hip/hip_bf16.h>

// ContrastiveLoss: loss = mean_i [ logsumexp_j(logits[i,:]) - pos_sim[i,i] ]
// logits = [20*xn@tn^T | 20*xn@hn^T + I], rows normalized.
// Round 20: amortize barriers/staging on the champion structure.
//  - R18/R19 falsify pipelining at BOTH residencies (52.2 / 55.7 vs R15
//    serial 45.6): implicit inter-block overlap already captures it (m114).
//    Serial 2-barrier schedule is the keeper.
//  - This round: tile 128x256, 512 thr (8 waves 2Mx4N of 64x64), BK=128,
//    LDS 48KB -> 2 blocks x 8 waves = 16 waves/CU (SAME wave count as R15,
//    unlike R12's failed 8-wave@8-waves/CU). Per CU lifetime: barrier
//    events halved (4 blocks x 16 vs 8 x 16), staged bytes -25% (1.5 vs
//    2 MB), rowsum atomics halved; MFMA + LDS-read pipes identical.
//  - Schedule, swizzle family, frag math, epilogue map: R15 verbatim.
//  - Ledger: no-LDS banned (R16); 32x32x32 banned (R17: 4.2M conflicts);
//    pipelining banned (R9/R10/R11/R18/R19); device fences banned (R14);
//    scaled-MFMA banned (R2/R4); b64 reads banned (R5); setprio off (m190).
//  - logit = acc * (20/127^2); diag cancellation keeps i8 loss error ~1e-3.

#define AS1 __attribute__((address_space(1)))
#define AS3 __attribute__((address_space(3)))

constexpr int N = 4096;
constexpr int D = 1024;            // elements per row == bytes per i8 row
constexpr float QSCALE = 127.0f;
constexpr float LSCALE = 20.0f / (127.0f * 127.0f);  // acc -> logit
constexpr float CBIAS = 21.0f;     // >= max possible logit (20*1 + 1)

typedef int i32x4 __attribute__((ext_vector_type(4)));

// 3072 blocks x 256. One row per wave, 4 coalesced passes: pass j, lane L
// loads float4 #(L+64j) (1KB/inst contiguous) and stores the 4 quantized
// bytes as u32 #(L+64j) (256B/inst contiguous).
// Blocks 0..15 zero rowsum; block 0 zeroes out[0] for finalize's atomics.
__global__ __launch_bounds__(256) void normalize_kernel(
    const float* __restrict__ in0, const float* __restrict__ in1,
    const float* __restrict__ in2, unsigned char* __restrict__ Abuf,
    unsigned char* __restrict__ Bbuf, float* __restrict__ rowsum,
    float* __restrict__ outp) {
    const int t = threadIdx.x, lane = t & 63, wave = t >> 6;
    if (blockIdx.x < 16) rowsum[blockIdx.x * 256 + t] = 0.f;
    if (blockIdx.x == 0 && t == 0) outp[0] = 0.f;
    const int row = blockIdx.x * 4 + wave;  // 0..12287
    const int mat = row >> 12, r = row & (N - 1);
    const float* src = (mat == 0) ? in0 : (mat == 1) ? in1 : in2;
    unsigned char* dst = (mat == 0) ? (Abuf + (size_t)r * D)
                       : (mat == 1) ? (Bbuf + (size_t)r * D)
                                    : (Bbuf + (size_t)(r + N) * D);
    const float4* s4 = (const float4*)(src + (size_t)r * D);
    float4 v[4];
    float p = 0.f;
#pragma unroll
    for (int j = 0; j < 4; ++j) {
        v[j] = s4[lane + 64 * j];  // coalesced: 64 consecutive float4/inst
        p += v[j].x * v[j].x + v[j].y * v[j].y + v[j].z * v[j].z + v[j].w * v[j].w;
    }
#pragma unroll
    for (int m = 1; m < 64; m <<= 1) p += __shfl_xor(p, m);
    const float s = QSCALE / fmaxf(sqrtf(p), 1e-8f);
    unsigned int* d32 = (unsigned int*)dst;
#pragma unroll
    for (int j = 0; j < 4; ++j) {
        int q0 = min(127, max(-127, __float2int_rn(v[j].x * s)));
        int q1 = min(127, max(-127, __float2int_rn(v[j].y * s)));
        int q2 = min(127, max(-127, __float2int_rn(v[j].z * s)));
        int q3 = min(127, max(-127, __float2int_rn(v[j].w * s)));
        d32[lane + 64 * j] = (q0 & 255) | ((q1 & 255) << 8) | ((q2 & 255) << 16)
                           | ((unsigned)(q3 & 255) << 24);
    }
}

// 128x256 tile, BK=128 i8-bytes, 8 waves (2M x 4N), wave 64x64 via 4x4 of
// 16x16x64 i8 MFMA, 2 K-substeps (h) per staged tile, b128 frag reads.
// A:[N,D] i8, B:[2N,D] i8, row-major (frag = 16 contig bytes,
// row = lane&15, k = (lane>>4)*16 + j).
// C/D: col = lane&15, row = (lane>>4)*4 + reg (m89-verified).
// __launch_bounds__(512,4): 2 blocks x 8 waves = 16 waves/CU (R13/R15's
// proven wave count), LDS 2 x 48KB = 96KB.
__global__ __launch_bounds__(512, 4) void gemm_lse_kernel(
    const unsigned char* __restrict__ A, const unsigned char* __restrict__ B,
    float* __restrict__ rowsum, float* __restrict__ posdiag) {
    __shared__ __align__(16) char As[128 * 128];  // 16 KiB
    __shared__ __align__(16) char Bs[256 * 128];  // 32 KiB

    const int tid = threadIdx.x;
    const int lane = tid & 63;
    const int wave = tid >> 6;       // 0..7
    const int wr = wave >> 2;        // 0..1 : 64-row half of A tile
    const int wc = wave & 3;         // 0..3 : 64-col chunk of B tile
    const int quad = lane >> 4, colid = lane & 15;

    // 2D XCD partition (R14/R15-proven mechanism): grid 32x32 tiles;
    // XCD x owns rows [16*(x>>2),+16) x cols [8*(x&3),+8) in tile units:
    // A 2MB + B 2MB concurrent -> fits 4MB per-XCD L2. Bijective:
    // tt=0..127 -> rowTile (xcd>>2)*16 + (tt&15), colTile (xcd&3)*8+(tt>>4).
    const int flat = blockIdx.y * 32 + blockIdx.x;
    const int xcd = flat & 7, tt = flat >> 3;  // tt = 0..127 within XCD
    const int rowBase = (((xcd >> 2) << 4) + (tt & 15)) * 128;
    const int colBase = (((xcd & 3) << 3) + (tt >> 4)) * 256;

    i32x4 acc[4][4];
#pragma unroll
    for (int i = 0; i < 4; ++i)
#pragma unroll
        for (int j = 0; j < 4; ++j) acc[i][j] = {0, 0, 0, 0};

    // Staging (R8/R15-proven 128B-row swizzle, 0 conflicts): 16B phys-chunk
    // c -> row c>>3, phys col c&7; logical col = (c&7)^(row&7). Thread t
    // (0..511): A chunks t, t+512 (rows t>>3, +64); B chunks t+512j
    // (rows t>>3 + 64j, j=0..3). scol j-invariant (row&7 preserved by +64).
    const int srow = tid >> 3;                      // 0..63
    const int scol = (tid & 7) ^ ((tid >> 3) & 7);  // 16B units
    const unsigned char* gA0 = A + (size_t)(rowBase + srow) * D + scol * 16;
    const unsigned char* gA1 = A + (size_t)(rowBase + srow + 64) * D + scol * 16;
    const unsigned char* gB[4];
#pragma unroll
    for (int j = 0; j < 4; ++j)
        gB[j] = B + (size_t)(colBase + srow + 64 * j) * D + scol * 16;

    // Frag offsets (R15 verbatim math): chunk for K-half h = (h*4+quad) ^
    // (colid&7); row R = (wr|wc)*64 + rt*16 + colid, R&7 == colid&7.
    // rt/ct stride 2048 folded into the read offset immediate.
    const int c0 = (quad ^ (colid & 7)) * 16;
    const int c1 = ((4 + quad) ^ (colid & 7)) * 16;
    const int arow = (wr * 64 + colid) * 128;
    const int brow = (wc * 64 + colid) * 128;
    const int aoff0 = arow + c0, aoff1 = arow + c1;
    const int boff0 = brow + c0, boff1 = brow + c1;

    for (int kb = 0; kb < D / 128; ++kb) {
        const int k0 = kb * 128;
        __syncthreads();  // prior reads done before overwrite
        __builtin_amdgcn_global_load_lds((const AS1 void*)(gA0 + k0),
            (AS3 void*)(As + tid * 16), 16, 0, 0);
        __builtin_amdgcn_global_load_lds((const AS1 void*)(gA1 + k0),
            (AS3 void*)(As + (tid + 512) * 16), 16, 0, 0);
#pragma unroll
        for (int j = 0; j < 4; ++j) {
            __builtin_amdgcn_global_load_lds((const AS1 void*)(gB[j] + k0),
                (AS3 void*)(Bs + (tid + 512 * j) * 16), 16, 0, 0);
        }
        __syncthreads();  // staged data visible

#pragma unroll
        for (int h = 0; h < 2; ++h) {
            const int ao = h ? aoff1 : aoff0;
            const int bo = h ? boff1 : boff0;
            i32x4 a[4], b[4];
#pragma unroll
            for (int rt = 0; rt < 4; ++rt)
                a[rt] = *(const i32x4*)(As + ao + rt * 2048);
#pragma unroll
            for (int ct = 0; ct < 4; ++ct)
                b[ct] = *(const i32x4*)(Bs + bo + ct * 2048);
#pragma unroll
            for (int rt = 0; rt < 4; ++rt)
#pragma unroll
                for (int ct = 0; ct < 4; ++ct)
                    acc[rt][ct] = __builtin_amdgcn_mfma_i32_16x16x64_i8(
                        a[rt], b[ct], acc[rt][ct], 0, 0, 0);
        }
    }

    // Epilogue: C map col = lane&15, row = quad*4 + reg (R15 verbatim).
#pragma unroll
    for (int rt = 0; rt < 4; ++rt) {
        float rsum[4] = {0.f, 0.f, 0.f, 0.f};
#pragma unroll
        for (int ct = 0; ct < 4; ++ct) {
#pragma unroll
            for (int reg = 0; reg < 4; ++reg) {
                const int grow = rowBase + wr * 64 + rt * 16 + quad * 4 + reg;
                const int gcol = colBase + wc * 64 + ct * 16 + colid;
                float logit = (float)acc[rt][ct][reg] * LSCALE;
                if (gcol == grow + N) logit += 1.0f;      // hard-negative weight
                if (gcol == grow) posdiag[grow] = logit;  // unique writer
                rsum[reg] += __expf(logit - CBIAS);
            }
        }
#pragma unroll
        for (int reg = 0; reg < 4; ++reg) {
            float v = rsum[reg];
            v += __shfl_xor(v, 1);
            v += __shfl_xor(v, 2);
            v += __shfl_xor(v, 4);
            v += __shfl_xor(v, 8);
            if (colid == 0) {
                const int grow = rowBase + wr * 64 + rt * 16 + quad * 4 + reg;
                atomicAdd(&rowsum[grow], v);
            }
        }
    }
}

// 16 blocks x 256 thr, one row per thread; wave-reduce then one atomic per
// wave into out (out zeroed by normalize earlier in the stream).
__global__ __launch_bounds__(256) void finalize_kernel(
    const float* __restrict__ rowsum, const float* __restrict__ posdiag,
    float* __restrict__ out) {
    const int i = blockIdx.x * 256 + threadIdx.x;
    float s = CBIAS + logf(rowsum[i]) - posdiag[i];
#pragma unroll
    for (int m = 32; m; m >>= 1) s += __shfl_down(s, m);
    if ((threadIdx.x & 63) == 0) atomicAdd(out, s * (1.0f / (float)N));
}

extern "C" void kernel_launch(void* const* d_in, const int* in_sizes, int n_in,
                              void* d_out, int out_size, void* d_ws, size_t ws_size,
                              hipStream_t stream) {
    const float* in0 = (const float*)d_in[0];  // input   [N, D] fp32
    const float* in1 = (const float*)d_in[1];  // target  [N, D] fp32
    const float* in2 = (const float*)d_in[2];  // hardneg [N, D] fp32

    // Workspace: Abuf N*D i8 (4 MiB) | Bbuf 2N*D i8 (8 MiB) | rowsum | posdiag
    unsigned char* Abuf = (unsigned char*)d_ws;
    unsigned char* Bbuf = Abuf + (size_t)N * D;
    float* rowsum = (float*)(Bbuf + (size_t)2 * N * D);
    float* posdiag = rowsum + N;

    normalize_kernel<<<3 * N / 4, 256, 0, stream>>>(in0, in1, in2, Abuf, Bbuf,
                                                    rowsum, (float*)d_out);
    gemm_lse_kernel<<<dim3(2 * N / 256, N / 128), 512, 0, stream>>>(
        Abuf, Bbuf, rowsum, posdiag);
    finalize_kernel<<<16, 256, 0, stream>>>(rowsum, posdiag, (float*)d_out);
}